// Round 13
// baseline (223.588 us; speedup 1.0000x reference)
//
#include <hip/hip_runtime.h>
#include <hip/hip_fp16.h>
#include <math.h>

// ARAP projection, 8 Adam steps. Multi-dispatch (16 dependent boundaries are
// structural: R needs all recon, grad needs all R; persistent/grid-sync
// refuted twice on this chip).
// R13 = R12 + (a) non-temporal loads on pure streams (we4h/nbr/acc) so the
// reused random-gather targets (rc, quat: 1.6MB) stay L2-resident,
// (b) Adam m/v packed fp16x8 in one uint4 (halves Adam-state traffic).

#define BLK 256
#define MAXK 8
#define NSTEP 8

union H4 { uint2 u; __half2 h[2]; };

__device__ __forceinline__ uint2 pack4(float a, float b, float c, float d) {
    H4 t;
    t.h[0] = __floats2half2_rn(a, b);
    t.h[1] = __floats2half2_rn(c, d);
    return t.u;
}
__device__ __forceinline__ void unpack4(uint2 u, float& a, float& b,
                                        float& c, float& d) {
    H4 t; t.u = u;
    float2 xy = __half22float2(t.h[0]);
    float2 zw = __half22float2(t.h[1]);
    a = xy.x; b = xy.y; c = zw.x; d = zw.y;
}

__device__ __forceinline__ uint2 ntload_u2(const uint2* p) {
    unsigned long long v =
        __builtin_nontemporal_load((const unsigned long long*)p);
    uint2 r; r.x = (unsigned)v; r.y = (unsigned)(v >> 32); return r;
}
__device__ __forceinline__ int ntload_i(const int* p) {
    return __builtin_nontemporal_load(p);
}

__global__ __launch_bounds__(BLK) void prep_kernel(
    const float* __restrict__ xyz, const float* __restrict__ recon0,
    const int* __restrict__ nbr, const int* __restrict__ num,
    const int* __restrict__ acc, const float* __restrict__ wm,
    uint2* __restrict__ we4h, float4* __restrict__ b4,
    uint2* __restrict__ rbufA, int n)
{
    int t = blockIdx.x * blockDim.x + threadIdx.x;
    int i = t >> 3, e = t & 7;
    if (i >= n) return;

    int e0 = acc[i];
    int cnt = num[i]; if (cnt > MAXK) cnt = MAXK;
    float xi0 = xyz[3*i+0], xi1 = xyz[3*i+1], xi2 = xyz[3*i+2];

    int j = i; float w = 0.f;
    if (e < cnt) { j = nbr[e0+e]; w = wm[e0+e]; }
    float we0 = w*(xi0 - xyz[3*j+0]);
    float we1 = w*(xi1 - xyz[3*j+1]);
    float we2 = w*(xi2 - xyz[3*j+2]);

    uint2 hv = pack4(we0, we1, we2, w);
    we4h[e0+e] = hv;

    // b from ROUNDED values (consistency with step kernels)
    float r0, r1, r2, rw;
    unpack4(hv, r0, r1, r2, rw);
    float b0 = r0, b1 = r1, b2 = r2;
#pragma unroll
    for (int m = 1; m < 8; m <<= 1) {
        b0 += __shfl_xor(b0, m);
        b1 += __shfl_xor(b1, m);
        b2 += __shfl_xor(b2, m);
    }
    if (e == 0) b4[i] = make_float4(b0, b1, b2, 0.f);
    if (e == 1) rbufA[i] = pack4(recon0[3*i+0], recon0[3*i+1],
                                 recon0[3*i+2], 0.f);
}

// ---- per step 1: S+pd accumulate (8 lanes/edge) + polar (threads 0-31) ----
__global__ __launch_bounds__(BLK) void rotq_kernel(
    const uint2* __restrict__ rc, const int* __restrict__ nbr,
    const int* __restrict__ acc, const uint2* __restrict__ we4h,
    const float4* __restrict__ b4, uint2* __restrict__ quat,
    float4* __restrict__ T4, int n)
{
    __shared__ float sS[32 * 13];
    int tid = threadIdx.x;
    int vloc = tid >> 3, e = tid & 7;
    int blockBase = blockIdx.x * 32;
    int v = blockBase + vloc;

    if (v < n) {
        int e0 = ntload_i(acc + v);
        float pi0, pi1, pi2, pw;
        unpack4(rc[v], pi0, pi1, pi2, pw);
        float wx, wy, wz, ww;
        unpack4(ntload_u2(we4h + e0 + e), wx, wy, wz, ww);
        int j = ntload_i(nbr + e0 + e);
        float pj0, pj1, pj2, qw_;
        unpack4(rc[j], pj0, pj1, pj2, qw_);
        float ed0 = pi0 - pj0, ed1 = pi1 - pj1, ed2 = pi2 - pj2;

        float S00 = wx*ed0, S01 = wx*ed1, S02 = wx*ed2;
        float S10 = wy*ed0, S11 = wy*ed1, S12 = wy*ed2;
        float S20 = wz*ed0, S21 = wz*ed1, S22 = wz*ed2;
        float pd0 = ww*ed0, pd1 = ww*ed1, pd2 = ww*ed2;

#pragma unroll
        for (int m = 1; m < 8; m <<= 1) {
            S00 += __shfl_xor(S00, m); S01 += __shfl_xor(S01, m); S02 += __shfl_xor(S02, m);
            S10 += __shfl_xor(S10, m); S11 += __shfl_xor(S11, m); S12 += __shfl_xor(S12, m);
            S20 += __shfl_xor(S20, m); S21 += __shfl_xor(S21, m); S22 += __shfl_xor(S22, m);
            pd0 += __shfl_xor(pd0, m); pd1 += __shfl_xor(pd1, m); pd2 += __shfl_xor(pd2, m);
        }
        float* p = &sS[vloc * 13];
        if (e == 0) { p[0] = S00; p[1] = S01; p[2]  = S02; p[3]  = pd0; }
        if (e == 1) { p[4] = S10; p[5] = S11; p[6]  = S12; p[7]  = pd1; }
        if (e == 2) { p[8] = S20; p[9] = S21; p[10] = S22; p[11] = pd2; }
    }
    __syncthreads();

    // polar: threads 0-31, one vertex each
    if (tid >= 32) return;
    v = blockBase + tid;
    if (v >= n) return;
    const float* p = &sS[tid * 13];
    float S00 = p[0], S01 = p[1], S02 = p[2],  pd0 = p[3];
    float S10 = p[4], S11 = p[5], S12 = p[6],  pd1 = p[7];
    float S20 = p[8], S21 = p[9], S22 = p[10], pd2 = p[11];

    float detS = S00*(S11*S22 - S12*S21)
               - S01*(S10*S22 - S12*S20)
               + S02*(S10*S21 - S11*S20);

    // A = S^T ; scaled Newton polar -> Q = V U^T, det(Q)=sign(det S)
    float A00 = S00, A01 = S10, A02 = S20;
    float A10 = S01, A11 = S11, A12 = S21;
    float A20 = S02, A21 = S12, A22 = S22;

    float fS = A00*A00+A01*A01+A02*A02+A10*A10+A11*A11+A12*A12
             + A20*A20+A21*A21+A22*A22;
    if (fS < 1e-24f) {
        A00=1.f; A01=0.f; A02=0.f;
        A10=0.f; A11=1.f; A12=0.f;
        A20=0.f; A21=0.f; A22=1.f;
    } else {
#pragma unroll
        for (int it = 0; it < 7; ++it) {
            float C00 = A11*A22 - A12*A21;
            float C01 = A12*A20 - A10*A22;
            float C02 = A10*A21 - A11*A20;
            float C10 = A02*A21 - A01*A22;
            float C11 = A00*A22 - A02*A20;
            float C12 = A01*A20 - A00*A21;
            float C20 = A01*A12 - A02*A11;
            float C21 = A02*A10 - A00*A12;
            float C22 = A00*A11 - A01*A10;
            float det = A00*C00 + A01*C01 + A02*C02;
            float ad = fmaxf(fabsf(det), 1e-30f);
            det = (det < 0.f) ? -ad : ad;
            float fA = A00*A00+A01*A01+A02*A02+A10*A10+A11*A11
                     + A12*A12+A20*A20+A21*A21+A22*A22;
            float fC = C00*C00+C01*C01+C02*C02+C10*C10+C11*C11
                     + C12*C12+C20*C20+C21*C21+C22*C22;
            float g = sqrtf(sqrtf(fC / fmaxf(ad*ad*fA, 1e-38f)));
            float s0 = 0.5f * g;
            float s1 = 0.5f / (g * det);
            A00 = s0*A00 + s1*C00; A01 = s0*A01 + s1*C01; A02 = s0*A02 + s1*C02;
            A10 = s0*A10 + s1*C10; A11 = s0*A11 + s1*C11; A12 = s0*A12 + s1*C12;
            A20 = s0*A20 + s1*C20; A21 = s0*A21 + s1*C21; A22 = s0*A22 + s1*C22;
        }

        if (detS < 0.f) {
            // R = Q (I - 2 u3 u3^T), u3 = min-eigvec of H = Q^T S^T
            float H00 = A00*S00 + A10*S01 + A20*S02;
            float H01 = A00*S10 + A10*S11 + A20*S12;
            float H02 = A00*S20 + A10*S21 + A20*S22;
            float H10 = A01*S00 + A11*S01 + A21*S02;
            float H11 = A01*S10 + A11*S11 + A21*S12;
            float H12 = A01*S20 + A11*S21 + A21*S22;
            float H20 = A02*S00 + A12*S01 + A22*S02;
            float H21 = A02*S10 + A12*S11 + A22*S12;
            float H22 = A02*S20 + A12*S21 + A22*S22;
            float h01 = 0.5f*(H01 + H10);
            float h02 = 0.5f*(H02 + H20);
            float h12 = 0.5f*(H12 + H21);

            float q  = (H00 + H11 + H22) * (1.f/3.f);
            float p1 = h01*h01 + h02*h02 + h12*h12;
            float a00 = H00 - q, a11 = H11 - q, a22 = H22 - q;
            float p2 = a00*a00 + a11*a11 + a22*a22 + 2.f*p1;
            float pp = sqrtf(fmaxf(p2 * (1.f/6.f), 1e-30f));
            float ip = 1.f / pp;
            float b00 = a00*ip, b01 = h01*ip, b02 = h02*ip;
            float b11 = a11*ip, b12 = h12*ip, b22 = a22*ip;
            float detB = b00*(b11*b22 - b12*b12)
                       - b01*(b01*b22 - b12*b02)
                       + b02*(b01*b12 - b11*b02);
            float r   = fminf(1.f, fmaxf(-1.f, 0.5f*detB));
            float phi = acosf(r) * (1.f/3.f);
            float l1 = q + 2.f*pp*cosf(phi);
            float l3 = q + 2.f*pp*cosf(phi + 2.0943951023931953f);
            float l2 = 3.f*q - l1 - l3;

            float m100 = H00-l1, m111 = H11-l1, m122 = H22-l1;
            float m200 = H00-l2, m211 = H11-l2, m222 = H22-l2;
            float P00 = m100*m200 + h01*h01 + h02*h02;
            float P10 = h01*m200 + m111*h01 + h12*h02;
            float P20 = h02*m200 + h12*h01 + m122*h02;
            float P01 = m100*h01 + h01*m211 + h02*h12;
            float P11 = h01*h01 + m111*m211 + h12*h12;
            float P21 = h02*h01 + h12*m211 + m122*h12;
            float P02 = m100*h02 + h01*h12 + h02*m222;
            float P12 = h01*h02 + m111*h12 + h12*m222;
            float P22 = h02*h02 + h12*h12 + m122*m222;

            float n0 = P00*P00 + P10*P10 + P20*P20;
            float n1 = P01*P01 + P11*P11 + P21*P21;
            float n2 = P02*P02 + P12*P12 + P22*P22;
            float u0, u1, u2, nn;
            if (n0 >= n1 && n0 >= n2) { u0=P00; u1=P10; u2=P20; nn=n0; }
            else if (n1 >= n2)        { u0=P01; u1=P11; u2=P21; nn=n1; }
            else                      { u0=P02; u1=P12; u2=P22; nn=n2; }
            if (nn > 1e-30f) {
                float inv = rsqrtf(nn);
                u0 *= inv; u1 *= inv; u2 *= inv;
                float Qu0 = A00*u0 + A01*u1 + A02*u2;
                float Qu1 = A10*u0 + A11*u1 + A12*u2;
                float Qu2 = A20*u0 + A21*u1 + A22*u2;
                A00 -= 2.f*Qu0*u0; A01 -= 2.f*Qu0*u1; A02 -= 2.f*Qu0*u2;
                A10 -= 2.f*Qu1*u0; A11 -= 2.f*Qu1*u1; A12 -= 2.f*Qu1*u2;
                A20 -= 2.f*Qu2*u0; A21 -= 2.f*Qu2*u1; A22 -= 2.f*Qu2*u2;
            }
        }
    }

    // T = 2*pd - R_i * b_i  (fp32)
    float4 b = b4[v];
    float T0 = 2.f*pd0 - (A00*b.x + A01*b.y + A02*b.z);
    float T1 = 2.f*pd1 - (A10*b.x + A11*b.y + A12*b.z);
    float T2 = 2.f*pd2 - (A20*b.x + A21*b.y + A22*b.z);
    T4[v] = make_float4(T0, T1, T2, 0.f);

    // rotation matrix -> quaternion (Shepperd), store fp16x4
    float qw, qx, qy, qz;
    float tr = A00 + A11 + A22;
    if (tr > 0.f) {
        float s = sqrtf(tr + 1.f) * 2.f;
        qw = 0.25f*s; float is = 1.f/s;
        qx = (A21 - A12)*is; qy = (A02 - A20)*is; qz = (A10 - A01)*is;
    } else if (A00 > A11 && A00 > A22) {
        float s = sqrtf(1.f + A00 - A11 - A22) * 2.f;
        qx = 0.25f*s; float is = 1.f/s;
        qw = (A21 - A12)*is; qy = (A01 + A10)*is; qz = (A02 + A20)*is;
    } else if (A11 > A22) {
        float s = sqrtf(1.f + A11 - A00 - A22) * 2.f;
        qy = 0.25f*s; float is = 1.f/s;
        qw = (A02 - A20)*is; qx = (A01 + A10)*is; qz = (A12 + A21)*is;
    } else {
        float s = sqrtf(1.f + A22 - A00 - A11) * 2.f;
        qz = 0.25f*s; float is = 1.f/s;
        qw = (A10 - A01)*is; qx = (A02 + A20)*is; qy = (A12 + A21)*is;
    }
    float inv = rsqrtf(qw*qw + qx*qx + qy*qy + qz*qz);
    quat[v] = pack4(qx*inv, qy*inv, qz*inv, qw*inv);
}

// ---- per step 2: gradient + Adam, edge-parallel ---------------------------
__global__ __launch_bounds__(BLK) void grad_kernel(
    const uint2* __restrict__ rc, const int* __restrict__ nbr,
    const int* __restrict__ acc, const uint2* __restrict__ we4h,
    const float* __restrict__ arapW, const uint2* __restrict__ quat,
    const float4* __restrict__ T4,
    uint4* __restrict__ mvbuf,
    uint2* __restrict__ rn, float* __restrict__ out,
    int n, int first, int last, float ib1, float ib2)
{
    int t = blockIdx.x * blockDim.x + threadIdx.x;
    int i = t >> 3, e = t & 7;
    if (i >= n) return;

    int e0 = ntload_i(acc + i);
    float wvx, wvy, wvz, wvw;
    unpack4(ntload_u2(we4h + e0 + e), wvx, wvy, wvz, wvw);
    int j = ntload_i(nbr + e0 + e);
    float x, y, z, w;
    unpack4(quat[j], x, y, z, w);

    // R_j from quaternion, times we (rows)
    float xx=x*x, yy=y*y, zz=z*z;
    float xy=x*y, xz=x*z, yz=y*z, wx=w*x, wy=w*y, wz=w*z;
    float c0 = (1.f-2.f*(yy+zz))*wvx + (2.f*(xy-wz))*wvy + (2.f*(xz+wy))*wvz;
    float c1 = (2.f*(xy+wz))*wvx + (1.f-2.f*(xx+zz))*wvy + (2.f*(yz-wx))*wvz;
    float c2 = (2.f*(xz-wy))*wvx + (2.f*(yz+wx))*wvy + (1.f-2.f*(xx+yy))*wvz;

#pragma unroll
    for (int m = 1; m < 8; m <<= 1) {
        c0 += __shfl_xor(c0, m);
        c1 += __shfl_xor(c1, m);
        c2 += __shfl_xor(c2, m);
    }

    if (e == 0) {
        float aw = arapW[0];
        float4 T = T4[i];
        float pi0, pi1, pi2, pw;
        unpack4(rc[i], pi0, pi1, pi2, pw);
        float g0 = aw * (T.x - c0);
        float g1 = aw * (T.y - c1);
        float g2 = aw * (T.z - c2);

        float m0, m1, m2, v0, v1, v2;
        if (first) {
            m0 = 0.1f*g0; m1 = 0.1f*g1; m2 = 0.1f*g2;
            v0 = 0.001f*g0*g0; v1 = 0.001f*g1*g1; v2 = 0.001f*g2*g2;
        } else {
            uint4 mv = mvbuf[i];
            float om0, om1, om2, ov0, ov1, ov2, d0, d1;
            unpack4(make_uint2(mv.x, mv.y), om0, om1, om2, ov0);
            unpack4(make_uint2(mv.z, mv.w), ov1, ov2, d0, d1);
            m0 = 0.9f*om0 + 0.1f*g0;
            m1 = 0.9f*om1 + 0.1f*g1;
            m2 = 0.9f*om2 + 0.1f*g2;
            v0 = 0.999f*ov0 + 0.001f*g0*g0;
            v1 = 0.999f*ov1 + 0.001f*g1*g1;
            v2 = 0.999f*ov2 + 0.001f*g2*g2;
        }
        uint2 lo = pack4(m0, m1, m2, v0);
        uint2 hi = pack4(v1, v2, 0.f, 0.f);
        mvbuf[i] = make_uint4(lo.x, lo.y, hi.x, hi.y);

        // use the ROUNDED m/v (what the next step will read) for this
        // step's update only when exactness doesn't matter; reference uses
        // exact fp32 chain, so update with the fp32 values computed above.
        const float RATE = 0.01f, EPS = 1e-9f;
        float o0 = pi0 - RATE * ((m0*ib1) / (sqrtf(v0*ib2) + EPS));
        float o1 = pi1 - RATE * ((m1*ib1) / (sqrtf(v1*ib2) + EPS));
        float o2 = pi2 - RATE * ((m2*ib1) / (sqrtf(v2*ib2) + EPS));

        if (last) {
            out[3*(size_t)i+0] = o0;
            out[3*(size_t)i+1] = o1;
            out[3*(size_t)i+2] = o2;
        } else {
            rn[i] = pack4(o0, o1, o2, 0.f);
        }
    }
}

extern "C" void kernel_launch(void* const* d_in, const int* in_sizes, int n_in,
                              void* d_out, int out_size, void* d_ws, size_t ws_size,
                              hipStream_t stream) {
    const float* xyz    = (const float*)d_in[0];
    const float* recon0 = (const float*)d_in[1];
    const int*   nbr    = (const int*)d_in[2];
    const int*   num    = (const int*)d_in[3];
    const int*   acc    = (const int*)d_in[4];
    const float* wm     = (const float*)d_in[5];
    const float* aw     = (const float*)d_in[6];

    int n = in_sizes[0] / 3;
    int E = in_sizes[2];
    float* out = (float*)d_out;

    uint2*  we4h  = (uint2*)d_ws;                        // E (8B)
    float4* b4    = (float4*)(we4h + (size_t)E);         // n
    float4* T4    = b4    + (size_t)n;                   // n
    uint4*  mvbuf = (uint4*)(T4 + (size_t)n);            // n (16B)
    uint2*  rbufA = (uint2*)(mvbuf + (size_t)n);         // n (8B)
    uint2*  rbufB = rbufA + (size_t)n;                   // n (8B)
    uint2*  quat  = rbufB + (size_t)n;                   // n (8B)

    int gridR = (n + 31) / 32;                     // rotq: 32 vtx/block
    int gridE = ((size_t)n * 8 + BLK - 1) / BLK;   // 8 lanes/vertex

    prep_kernel<<<gridE, BLK, 0, stream>>>(xyz, recon0, nbr, num, acc, wm,
                                           we4h, b4, rbufA, n);

    const uint2* rc = rbufA;
    uint2*       rn = rbufB;
    for (int step = 1; step <= NSTEP; ++step) {
        rotq_kernel<<<gridR, BLK, 0, stream>>>(rc, nbr, acc, we4h, b4,
                                               quat, T4, n);
        float ib1 = 1.0f / (1.0f - powf(0.9f,   (float)step));
        float ib2 = 1.0f / (1.0f - powf(0.999f, (float)step));
        grad_kernel<<<gridE, BLK, 0, stream>>>(rc, nbr, acc, we4h, aw, quat,
                                               T4, mvbuf, rn, out,
                                               n, step == 1 ? 1 : 0,
                                               step == NSTEP ? 1 : 0, ib1, ib2);
        const uint2* tmp = rc; rc = rn; rn = (uint2*)tmp;
    }
}

// Round 14
// 202.474 us; speedup vs baseline: 1.1043x; 1.1043x over previous
//
#include <hip/hip_runtime.h>
#include <hip/hip_fp16.h>
#include <math.h>

// ARAP projection, 8 Adam steps. Multi-dispatch (16 dependent boundaries are
// structural; persistent/grid-sync refuted twice on this chip).
// R14 = R12 + fp16x8 Adam m/v ONLY. R13's nt-loads REVERTED: we4h/nbr/acc
// are read twice per step (rotq then grad) — marking them non-temporal
// evicted them between the two kernels and cost +16us.

#define BLK 256
#define MAXK 8
#define NSTEP 8

union H4 { uint2 u; __half2 h[2]; };

__device__ __forceinline__ uint2 pack4(float a, float b, float c, float d) {
    H4 t;
    t.h[0] = __floats2half2_rn(a, b);
    t.h[1] = __floats2half2_rn(c, d);
    return t.u;
}
__device__ __forceinline__ void unpack4(uint2 u, float& a, float& b,
                                        float& c, float& d) {
    H4 t; t.u = u;
    float2 xy = __half22float2(t.h[0]);
    float2 zw = __half22float2(t.h[1]);
    a = xy.x; b = xy.y; c = zw.x; d = zw.y;
}

__global__ __launch_bounds__(BLK) void prep_kernel(
    const float* __restrict__ xyz, const float* __restrict__ recon0,
    const int* __restrict__ nbr, const int* __restrict__ num,
    const int* __restrict__ acc, const float* __restrict__ wm,
    uint2* __restrict__ we4h, float4* __restrict__ b4,
    uint2* __restrict__ rbufA, int n)
{
    int t = blockIdx.x * blockDim.x + threadIdx.x;
    int i = t >> 3, e = t & 7;
    if (i >= n) return;

    int e0 = acc[i];
    int cnt = num[i]; if (cnt > MAXK) cnt = MAXK;
    float xi0 = xyz[3*i+0], xi1 = xyz[3*i+1], xi2 = xyz[3*i+2];

    int j = i; float w = 0.f;
    if (e < cnt) { j = nbr[e0+e]; w = wm[e0+e]; }
    float we0 = w*(xi0 - xyz[3*j+0]);
    float we1 = w*(xi1 - xyz[3*j+1]);
    float we2 = w*(xi2 - xyz[3*j+2]);

    uint2 hv = pack4(we0, we1, we2, w);
    we4h[e0+e] = hv;

    // b from ROUNDED values (consistency with step kernels)
    float r0, r1, r2, rw;
    unpack4(hv, r0, r1, r2, rw);
    float b0 = r0, b1 = r1, b2 = r2;
#pragma unroll
    for (int m = 1; m < 8; m <<= 1) {
        b0 += __shfl_xor(b0, m);
        b1 += __shfl_xor(b1, m);
        b2 += __shfl_xor(b2, m);
    }
    if (e == 0) b4[i] = make_float4(b0, b1, b2, 0.f);
    if (e == 1) rbufA[i] = pack4(recon0[3*i+0], recon0[3*i+1],
                                 recon0[3*i+2], 0.f);
}

// ---- per step 1: S+pd accumulate (8 lanes/edge) + polar (threads 0-31) ----
__global__ __launch_bounds__(BLK) void rotq_kernel(
    const uint2* __restrict__ rc, const int* __restrict__ nbr,
    const int* __restrict__ acc, const uint2* __restrict__ we4h,
    const float4* __restrict__ b4, uint2* __restrict__ quat,
    float4* __restrict__ T4, int n)
{
    __shared__ float sS[32 * 13];
    int tid = threadIdx.x;
    int vloc = tid >> 3, e = tid & 7;
    int blockBase = blockIdx.x * 32;
    int v = blockBase + vloc;

    if (v < n) {
        int e0 = acc[v];
        float pi0, pi1, pi2, pw;
        unpack4(rc[v], pi0, pi1, pi2, pw);
        float wx, wy, wz, ww;
        unpack4(we4h[e0+e], wx, wy, wz, ww);
        int j = nbr[e0+e];
        float pj0, pj1, pj2, qw_;
        unpack4(rc[j], pj0, pj1, pj2, qw_);
        float ed0 = pi0 - pj0, ed1 = pi1 - pj1, ed2 = pi2 - pj2;

        float S00 = wx*ed0, S01 = wx*ed1, S02 = wx*ed2;
        float S10 = wy*ed0, S11 = wy*ed1, S12 = wy*ed2;
        float S20 = wz*ed0, S21 = wz*ed1, S22 = wz*ed2;
        float pd0 = ww*ed0, pd1 = ww*ed1, pd2 = ww*ed2;

#pragma unroll
        for (int m = 1; m < 8; m <<= 1) {
            S00 += __shfl_xor(S00, m); S01 += __shfl_xor(S01, m); S02 += __shfl_xor(S02, m);
            S10 += __shfl_xor(S10, m); S11 += __shfl_xor(S11, m); S12 += __shfl_xor(S12, m);
            S20 += __shfl_xor(S20, m); S21 += __shfl_xor(S21, m); S22 += __shfl_xor(S22, m);
            pd0 += __shfl_xor(pd0, m); pd1 += __shfl_xor(pd1, m); pd2 += __shfl_xor(pd2, m);
        }
        float* p = &sS[vloc * 13];
        if (e == 0) { p[0] = S00; p[1] = S01; p[2]  = S02; p[3]  = pd0; }
        if (e == 1) { p[4] = S10; p[5] = S11; p[6]  = S12; p[7]  = pd1; }
        if (e == 2) { p[8] = S20; p[9] = S21; p[10] = S22; p[11] = pd2; }
    }
    __syncthreads();

    // polar: threads 0-31, one vertex each
    if (tid >= 32) return;
    v = blockBase + tid;
    if (v >= n) return;
    const float* p = &sS[tid * 13];
    float S00 = p[0], S01 = p[1], S02 = p[2],  pd0 = p[3];
    float S10 = p[4], S11 = p[5], S12 = p[6],  pd1 = p[7];
    float S20 = p[8], S21 = p[9], S22 = p[10], pd2 = p[11];

    float detS = S00*(S11*S22 - S12*S21)
               - S01*(S10*S22 - S12*S20)
               + S02*(S10*S21 - S11*S20);

    // A = S^T ; scaled Newton polar -> Q = V U^T, det(Q)=sign(det S)
    float A00 = S00, A01 = S10, A02 = S20;
    float A10 = S01, A11 = S11, A12 = S21;
    float A20 = S02, A21 = S12, A22 = S22;

    float fS = A00*A00+A01*A01+A02*A02+A10*A10+A11*A11+A12*A12
             + A20*A20+A21*A21+A22*A22;
    if (fS < 1e-24f) {
        A00=1.f; A01=0.f; A02=0.f;
        A10=0.f; A11=1.f; A12=0.f;
        A20=0.f; A21=0.f; A22=1.f;
    } else {
#pragma unroll
        for (int it = 0; it < 7; ++it) {
            float C00 = A11*A22 - A12*A21;
            float C01 = A12*A20 - A10*A22;
            float C02 = A10*A21 - A11*A20;
            float C10 = A02*A21 - A01*A22;
            float C11 = A00*A22 - A02*A20;
            float C12 = A01*A20 - A00*A21;
            float C20 = A01*A12 - A02*A11;
            float C21 = A02*A10 - A00*A12;
            float C22 = A00*A11 - A01*A10;
            float det = A00*C00 + A01*C01 + A02*C02;
            float ad = fmaxf(fabsf(det), 1e-30f);
            det = (det < 0.f) ? -ad : ad;
            float fA = A00*A00+A01*A01+A02*A02+A10*A10+A11*A11
                     + A12*A12+A20*A20+A21*A21+A22*A22;
            float fC = C00*C00+C01*C01+C02*C02+C10*C10+C11*C11
                     + C12*C12+C20*C20+C21*C21+C22*C22;
            float g = sqrtf(sqrtf(fC / fmaxf(ad*ad*fA, 1e-38f)));
            float s0 = 0.5f * g;
            float s1 = 0.5f / (g * det);
            A00 = s0*A00 + s1*C00; A01 = s0*A01 + s1*C01; A02 = s0*A02 + s1*C02;
            A10 = s0*A10 + s1*C10; A11 = s0*A11 + s1*C11; A12 = s0*A12 + s1*C12;
            A20 = s0*A20 + s1*C20; A21 = s0*A21 + s1*C21; A22 = s0*A22 + s1*C22;
        }

        if (detS < 0.f) {
            // R = Q (I - 2 u3 u3^T), u3 = min-eigvec of H = Q^T S^T
            float H00 = A00*S00 + A10*S01 + A20*S02;
            float H01 = A00*S10 + A10*S11 + A20*S12;
            float H02 = A00*S20 + A10*S21 + A20*S22;
            float H10 = A01*S00 + A11*S01 + A21*S02;
            float H11 = A01*S10 + A11*S11 + A21*S12;
            float H12 = A01*S20 + A11*S21 + A21*S22;
            float H20 = A02*S00 + A12*S01 + A22*S02;
            float H21 = A02*S10 + A12*S11 + A22*S12;
            float H22 = A02*S20 + A12*S21 + A22*S22;
            float h01 = 0.5f*(H01 + H10);
            float h02 = 0.5f*(H02 + H20);
            float h12 = 0.5f*(H12 + H21);

            float q  = (H00 + H11 + H22) * (1.f/3.f);
            float p1 = h01*h01 + h02*h02 + h12*h12;
            float a00 = H00 - q, a11 = H11 - q, a22 = H22 - q;
            float p2 = a00*a00 + a11*a11 + a22*a22 + 2.f*p1;
            float pp = sqrtf(fmaxf(p2 * (1.f/6.f), 1e-30f));
            float ip = 1.f / pp;
            float b00 = a00*ip, b01 = h01*ip, b02 = h02*ip;
            float b11 = a11*ip, b12 = h12*ip, b22 = a22*ip;
            float detB = b00*(b11*b22 - b12*b12)
                       - b01*(b01*b22 - b12*b02)
                       + b02*(b01*b12 - b11*b02);
            float r   = fminf(1.f, fmaxf(-1.f, 0.5f*detB));
            float phi = acosf(r) * (1.f/3.f);
            float l1 = q + 2.f*pp*cosf(phi);
            float l3 = q + 2.f*pp*cosf(phi + 2.0943951023931953f);
            float l2 = 3.f*q - l1 - l3;

            float m100 = H00-l1, m111 = H11-l1, m122 = H22-l1;
            float m200 = H00-l2, m211 = H11-l2, m222 = H22-l2;
            float P00 = m100*m200 + h01*h01 + h02*h02;
            float P10 = h01*m200 + m111*h01 + h12*h02;
            float P20 = h02*m200 + h12*h01 + m122*h02;
            float P01 = m100*h01 + h01*m211 + h02*h12;
            float P11 = h01*h01 + m111*m211 + h12*h12;
            float P21 = h02*h01 + h12*m211 + m122*h12;
            float P02 = m100*h02 + h01*h12 + h02*m222;
            float P12 = h01*h02 + m111*h12 + h12*m222;
            float P22 = h02*h02 + h12*h12 + m122*m222;

            float n0 = P00*P00 + P10*P10 + P20*P20;
            float n1 = P01*P01 + P11*P11 + P21*P21;
            float n2 = P02*P02 + P12*P12 + P22*P22;
            float u0, u1, u2, nn;
            if (n0 >= n1 && n0 >= n2) { u0=P00; u1=P10; u2=P20; nn=n0; }
            else if (n1 >= n2)        { u0=P01; u1=P11; u2=P21; nn=n1; }
            else                      { u0=P02; u1=P12; u2=P22; nn=n2; }
            if (nn > 1e-30f) {
                float inv = rsqrtf(nn);
                u0 *= inv; u1 *= inv; u2 *= inv;
                float Qu0 = A00*u0 + A01*u1 + A02*u2;
                float Qu1 = A10*u0 + A11*u1 + A12*u2;
                float Qu2 = A20*u0 + A21*u1 + A22*u2;
                A00 -= 2.f*Qu0*u0; A01 -= 2.f*Qu0*u1; A02 -= 2.f*Qu0*u2;
                A10 -= 2.f*Qu1*u0; A11 -= 2.f*Qu1*u1; A12 -= 2.f*Qu1*u2;
                A20 -= 2.f*Qu2*u0; A21 -= 2.f*Qu2*u1; A22 -= 2.f*Qu2*u2;
            }
        }
    }

    // T = 2*pd - R_i * b_i  (fp32)
    float4 b = b4[v];
    float T0 = 2.f*pd0 - (A00*b.x + A01*b.y + A02*b.z);
    float T1 = 2.f*pd1 - (A10*b.x + A11*b.y + A12*b.z);
    float T2 = 2.f*pd2 - (A20*b.x + A21*b.y + A22*b.z);
    T4[v] = make_float4(T0, T1, T2, 0.f);

    // rotation matrix -> quaternion (Shepperd), store fp16x4
    float qw, qx, qy, qz;
    float tr = A00 + A11 + A22;
    if (tr > 0.f) {
        float s = sqrtf(tr + 1.f) * 2.f;
        qw = 0.25f*s; float is = 1.f/s;
        qx = (A21 - A12)*is; qy = (A02 - A20)*is; qz = (A10 - A01)*is;
    } else if (A00 > A11 && A00 > A22) {
        float s = sqrtf(1.f + A00 - A11 - A22) * 2.f;
        qx = 0.25f*s; float is = 1.f/s;
        qw = (A21 - A12)*is; qy = (A01 + A10)*is; qz = (A02 + A20)*is;
    } else if (A11 > A22) {
        float s = sqrtf(1.f + A11 - A00 - A22) * 2.f;
        qy = 0.25f*s; float is = 1.f/s;
        qw = (A02 - A20)*is; qx = (A01 + A10)*is; qz = (A12 + A21)*is;
    } else {
        float s = sqrtf(1.f + A22 - A00 - A11) * 2.f;
        qz = 0.25f*s; float is = 1.f/s;
        qw = (A10 - A01)*is; qx = (A02 + A20)*is; qy = (A12 + A21)*is;
    }
    float inv = rsqrtf(qw*qw + qx*qx + qy*qy + qz*qz);
    quat[v] = pack4(qx*inv, qy*inv, qz*inv, qw*inv);
}

// ---- per step 2: gradient + Adam, edge-parallel ---------------------------
__global__ __launch_bounds__(BLK) void grad_kernel(
    const uint2* __restrict__ rc, const int* __restrict__ nbr,
    const int* __restrict__ acc, const uint2* __restrict__ we4h,
    const float* __restrict__ arapW, const uint2* __restrict__ quat,
    const float4* __restrict__ T4,
    uint4* __restrict__ mvbuf,
    uint2* __restrict__ rn, float* __restrict__ out,
    int n, int first, int last, float ib1, float ib2)
{
    int t = blockIdx.x * blockDim.x + threadIdx.x;
    int i = t >> 3, e = t & 7;
    if (i >= n) return;

    int e0 = acc[i];
    float wvx, wvy, wvz, wvw;
    unpack4(we4h[e0+e], wvx, wvy, wvz, wvw);
    int j = nbr[e0+e];
    float x, y, z, w;
    unpack4(quat[j], x, y, z, w);

    // R_j from quaternion, times we (rows)
    float xx=x*x, yy=y*y, zz=z*z;
    float xy=x*y, xz=x*z, yz=y*z, wx=w*x, wy=w*y, wz=w*z;
    float c0 = (1.f-2.f*(yy+zz))*wvx + (2.f*(xy-wz))*wvy + (2.f*(xz+wy))*wvz;
    float c1 = (2.f*(xy+wz))*wvx + (1.f-2.f*(xx+zz))*wvy + (2.f*(yz-wx))*wvz;
    float c2 = (2.f*(xz-wy))*wvx + (2.f*(yz+wx))*wvy + (1.f-2.f*(xx+yy))*wvz;

#pragma unroll
    for (int m = 1; m < 8; m <<= 1) {
        c0 += __shfl_xor(c0, m);
        c1 += __shfl_xor(c1, m);
        c2 += __shfl_xor(c2, m);
    }

    if (e == 0) {
        float aw = arapW[0];
        float4 T = T4[i];
        float pi0, pi1, pi2, pw;
        unpack4(rc[i], pi0, pi1, pi2, pw);
        float g0 = aw * (T.x - c0);
        float g1 = aw * (T.y - c1);
        float g2 = aw * (T.z - c2);

        float m0, m1, m2, v0, v1, v2;
        if (first) {
            m0 = 0.1f*g0; m1 = 0.1f*g1; m2 = 0.1f*g2;
            v0 = 0.001f*g0*g0; v1 = 0.001f*g1*g1; v2 = 0.001f*g2*g2;
        } else {
            uint4 mv = mvbuf[i];
            float om0, om1, om2, ov0, ov1, ov2, d0, d1;
            unpack4(make_uint2(mv.x, mv.y), om0, om1, om2, ov0);
            unpack4(make_uint2(mv.z, mv.w), ov1, ov2, d0, d1);
            m0 = 0.9f*om0 + 0.1f*g0;
            m1 = 0.9f*om1 + 0.1f*g1;
            m2 = 0.9f*om2 + 0.1f*g2;
            v0 = 0.999f*ov0 + 0.001f*g0*g0;
            v1 = 0.999f*ov1 + 0.001f*g1*g1;
            v2 = 0.999f*ov2 + 0.001f*g2*g2;
        }
        uint2 lo = pack4(m0, m1, m2, v0);
        uint2 hi = pack4(v1, v2, 0.f, 0.f);
        mvbuf[i] = make_uint4(lo.x, lo.y, hi.x, hi.y);

        const float RATE = 0.01f, EPS = 1e-9f;
        float o0 = pi0 - RATE * ((m0*ib1) / (sqrtf(v0*ib2) + EPS));
        float o1 = pi1 - RATE * ((m1*ib1) / (sqrtf(v1*ib2) + EPS));
        float o2 = pi2 - RATE * ((m2*ib1) / (sqrtf(v2*ib2) + EPS));

        if (last) {
            out[3*(size_t)i+0] = o0;
            out[3*(size_t)i+1] = o1;
            out[3*(size_t)i+2] = o2;
        } else {
            rn[i] = pack4(o0, o1, o2, 0.f);
        }
    }
}

extern "C" void kernel_launch(void* const* d_in, const int* in_sizes, int n_in,
                              void* d_out, int out_size, void* d_ws, size_t ws_size,
                              hipStream_t stream) {
    const float* xyz    = (const float*)d_in[0];
    const float* recon0 = (const float*)d_in[1];
    const int*   nbr    = (const int*)d_in[2];
    const int*   num    = (const int*)d_in[3];
    const int*   acc    = (const int*)d_in[4];
    const float* wm     = (const float*)d_in[5];
    const float* aw     = (const float*)d_in[6];

    int n = in_sizes[0] / 3;
    int E = in_sizes[2];
    float* out = (float*)d_out;

    uint2*  we4h  = (uint2*)d_ws;                        // E (8B)
    float4* b4    = (float4*)(we4h + (size_t)E);         // n
    float4* T4    = b4    + (size_t)n;                   // n
    uint4*  mvbuf = (uint4*)(T4 + (size_t)n);            // n (16B)
    uint2*  rbufA = (uint2*)(mvbuf + (size_t)n);         // n (8B)
    uint2*  rbufB = rbufA + (size_t)n;                   // n (8B)
    uint2*  quat  = rbufB + (size_t)n;                   // n (8B)

    int gridR = (n + 31) / 32;                     // rotq: 32 vtx/block
    int gridE = ((size_t)n * 8 + BLK - 1) / BLK;   // 8 lanes/vertex

    prep_kernel<<<gridE, BLK, 0, stream>>>(xyz, recon0, nbr, num, acc, wm,
                                           we4h, b4, rbufA, n);

    const uint2* rc = rbufA;
    uint2*       rn = rbufB;
    for (int step = 1; step <= NSTEP; ++step) {
        rotq_kernel<<<gridR, BLK, 0, stream>>>(rc, nbr, acc, we4h, b4,
                                               quat, T4, n);
        float ib1 = 1.0f / (1.0f - powf(0.9f,   (float)step));
        float ib2 = 1.0f / (1.0f - powf(0.999f, (float)step));
        grad_kernel<<<gridE, BLK, 0, stream>>>(rc, nbr, acc, we4h, aw, quat,
                                               T4, mvbuf, rn, out,
                                               n, step == 1 ? 1 : 0,
                                               step == NSTEP ? 1 : 0, ib1, ib2);
        const uint2* tmp = rc; rc = rn; rn = (uint2*)tmp;
    }
}